// Round 2
// baseline (587.241 us; speedup 1.0000x reference)
//
#include <hip/hip_runtime.h>
#include <hip/hip_bf16.h>
#include <cstddef>

#define NRB 100000      // robot nodes
#define NBL 100000      // ball nodes
#define NEDGE 600000    // edges per edge type
#define NSEG 300000     // concatenated dst space: [rr | rb | br], 100k each
// dims: 128 -> 128 -> 64
// NOTE: harness delivers integer inputs as int32 (edge indices are const int*).

typedef __attribute__((ext_vector_type(8))) short short8;
typedef __attribute__((ext_vector_type(4))) float floatx4;

// ---------------- CSR build (merged) ----------------

__global__ __launch_bounds__(256) void deg_all_kernel(const int* __restrict__ ei0,
                                                      const int* __restrict__ ei1,
                                                      const int* __restrict__ ei2,
                                                      int* __restrict__ deg) {
    int e = blockIdx.x * 256 + threadIdx.x;
    if (e >= NEDGE) return;
    const int* ei = (blockIdx.y == 0) ? ei0 : ((blockIdx.y == 1) ? ei1 : ei2);
    atomicAdd(&deg[blockIdx.y * 100000 + ei[NEDGE + e]], 1);
}

__global__ __launch_bounds__(256) void scan1_kernel(const int* __restrict__ deg,
                                                    int* __restrict__ rowstart,
                                                    int* __restrict__ bsum) {
    __shared__ int sh[256];
    int t = threadIdx.x, blk = blockIdx.x;
    int base = blk * 1024 + t * 4;
    int v0 = (base + 0 < NSEG) ? deg[base + 0] : 0;
    int v1 = (base + 1 < NSEG) ? deg[base + 1] : 0;
    int v2 = (base + 2 < NSEG) ? deg[base + 2] : 0;
    int v3 = (base + 3 < NSEG) ? deg[base + 3] : 0;
    int tsum = v0 + v1 + v2 + v3;
    sh[t] = tsum; __syncthreads();
    for (int off = 1; off < 256; off <<= 1) {
        int x = (t >= off) ? sh[t - off] : 0;
        __syncthreads();
        sh[t] += x;
        __syncthreads();
    }
    int excl = sh[t] - tsum;
    if (t == 255) bsum[blk] = sh[255];
    if (base + 0 <= NSEG) rowstart[base + 0] = excl;
    if (base + 1 <= NSEG) rowstart[base + 1] = excl + v0;
    if (base + 2 <= NSEG) rowstart[base + 2] = excl + v0 + v1;
    if (base + 3 <= NSEG) rowstart[base + 3] = excl + v0 + v1 + v2;
}

__global__ __launch_bounds__(512) void scan2_kernel(int* __restrict__ bsum, int nb) {
    __shared__ int sh[512];
    int t = threadIdx.x;
    int v = (t < nb) ? bsum[t] : 0;
    sh[t] = v; __syncthreads();
    for (int off = 1; off < 512; off <<= 1) {
        int x = (t >= off) ? sh[t - off] : 0;
        __syncthreads();
        sh[t] += x;
        __syncthreads();
    }
    if (t < nb) bsum[t] = sh[t] - v;   // exclusive
}

__global__ __launch_bounds__(256) void scan3_inv_kernel(int* __restrict__ rowstart,
                                                        const int* __restrict__ bsum,
                                                        const int* __restrict__ deg,
                                                        float* __restrict__ inv) {
    int t = threadIdx.x, blk = blockIdx.x;
    int add = bsum[blk];
    int base = blk * 1024 + t * 4;
    #pragma unroll
    for (int j = 0; j < 4; ++j) {
        if (base + j <= NSEG) rowstart[base + j] += add;
        if (base + j < NSEG) inv[base + j] = 1.0f / fmaxf((float)deg[base + j], 1.0f);
    }
}

__global__ __launch_bounds__(256) void fill_all_kernel(const int* __restrict__ ei0,
                                                       const int* __restrict__ ei1,
                                                       const int* __restrict__ ei2,
                                                       const int* __restrict__ rowstart,
                                                       int* __restrict__ cursor,
                                                       int* __restrict__ col) {
    int e = blockIdx.x * 256 + threadIdx.x;
    if (e >= NEDGE) return;
    const int* ei = (blockIdx.y == 0) ? ei0 : ((blockIdx.y == 1) ? ei1 : ei2);
    int src = ei[e];
    int g = blockIdx.y * 100000 + ei[NEDGE + e];
    int pos = atomicAdd(&cursor[g], 1);
    col[rowstart[g] + pos] = src;
}

// ---------------- weight prep (one launch) ----------------
__global__ __launch_bounds__(256) void wprep_all_kernel(
    const float* Wl0_rb, const float* Wl0_rr, const float* Wr0_rr, const float* Wr0_br,
    const float* Wl0_br, const float* Wr0_rb,
    const float* Wl1_br, const float* Wl1_rr, const float* Wr1_rr, const float* Wr1_br,
    const float* b0_rr, const float* b0_br, const float* b1_rr, const float* b1_br,
    __hip_bfloat16* WT1, __hip_bfloat16* WT2, __hip_bfloat16* WT3, __hip_bfloat16* WT4,
    float* bsum0, float* bsum1)
{
    int job = blockIdx.y;
    int t = blockIdx.x * 256 + threadIdx.x;
    if (job == 8) {
        if (t < 128) bsum0[t] = b0_rr[t] + b0_br[t];
        else if (t < 192) bsum1[t - 128] = b1_rr[t - 128] + b1_br[t - 128];
        return;
    }
    const float* A = nullptr; const float* B = nullptr;
    __hip_bfloat16* dst = nullptr; int dout = 128;
    switch (job) {
        case 0: A = Wl0_rb; dst = WT1;                 break;
        case 1: A = Wl0_rr; dst = WT1 + 128 * 128;     break;
        case 2: A = Wr0_rr; B = Wr0_br; dst = WT1 + 2 * 128 * 128; break;
        case 3: A = Wl0_br; dst = WT2;                 break;
        case 4: A = Wr0_rb; dst = WT2 + 128 * 128;     break;
        case 5: A = Wl1_br; dst = WT3;       dout = 64; break;
        case 6: A = Wl1_rr; dst = WT4;       dout = 64; break;
        case 7: A = Wr1_rr; B = Wr1_br; dst = WT4 + 64 * 128; dout = 64; break;
    }
    if (t >= dout * 128) return;
    int k = t & 127, n = t >> 7;
    float v = A[k * dout + n];
    if (B != nullptr) v += B[k * dout + n];
    dst[n * 128 + k] = __float2bfloat16(v);
}

// ---------------- MFMA GEMMs ----------------
// One output slice per block (grid.x = slice, grid.y = M-tile) so A-tile
// staging feeds exactly one compute phase; Es epilogue buffer ALIASES As
// (extra __syncthreads between last frag read and first Es write) -> LDS
// 52KB -> 34.8KB -> 4 blocks/CU instead of 3, and 2.5x more blocks.
// Same-bm slice blocks are adjacent in dispatch order -> shared A tile in
// cache; re-reads of x are L3-served (FETCH_SIZE 71MB < inputs already).

union Pack8 { __hip_bfloat16 h[8]; int4 v; };

// Layer 0: BN=128. slices: {0:y_rb,1:y_rr,2:sr} on A=x_robot; {3:y_br,4:sb} on A=x_ball.
__global__ __launch_bounds__(256, 4) void gemm_l0_kernel(
    const float* __restrict__ xr, const float* __restrict__ xb,
    const __hip_bfloat16* __restrict__ WT1, const __hip_bfloat16* __restrict__ WT2,
    __hip_bfloat16* __restrict__ y_rb, __hip_bfloat16* __restrict__ y_rr,
    __hip_bfloat16* __restrict__ sr,
    __hip_bfloat16* __restrict__ y_br, __hip_bfloat16* __restrict__ sb,
    const float* __restrict__ bsum0, const float* __restrict__ b0_rb)
{
    __shared__ __align__(16) char smem_[128 * 136 * 2];   // 34816 B
    __hip_bfloat16 (*As)[136] = (__hip_bfloat16 (*)[136])smem_;
    float (*Es)[16][68] = (float (*)[16][68])smem_;       // 17408 B, aliases As

    const int tid = threadIdx.x, sz = blockIdx.x, bm = blockIdx.y;
    const float* A = (sz < 3) ? xr : xb;
    const __hip_bfloat16* Wb = (sz < 3) ? (WT1 + (size_t)sz * 128 * 128)
                                        : (WT2 + (size_t)(sz - 3) * 128 * 128);
    __hip_bfloat16* op; const float* bp = nullptr;
    switch (sz) {
        case 0: op = y_rb; break;
        case 1: op = y_rr; break;
        case 2: op = sr; bp = bsum0; break;
        case 3: op = y_br; break;
        default: op = sb; bp = b0_rb; break;
    }
    const int c = tid & 15, rbase = tid >> 4;

    #pragma unroll
    for (int p = 0; p < 8; ++p) {
        int r = p * 16 + rbase;
        int gr = bm * 128 + r;
        float4 u = make_float4(0.f, 0.f, 0.f, 0.f), v = make_float4(0.f, 0.f, 0.f, 0.f);
        if (gr < NRB) {
            const float* src = A + (size_t)gr * 128 + c * 8;
            u = *(const float4*)(src);
            v = *(const float4*)(src + 4);
        }
        Pack8 pk;
        *(__hip_bfloat162*)&pk.h[0] = __float22bfloat162_rn(make_float2(u.x, u.y));
        *(__hip_bfloat162*)&pk.h[2] = __float22bfloat162_rn(make_float2(u.z, u.w));
        *(__hip_bfloat162*)&pk.h[4] = __float22bfloat162_rn(make_float2(v.x, v.y));
        *(__hip_bfloat162*)&pk.h[6] = __float22bfloat162_rn(make_float2(v.z, v.w));
        *(int4*)&As[r][c * 8] = pk.v;
    }
    __syncthreads();

    const int wave = tid >> 6, lane = tid & 63;
    const int wm = wave >> 1, wn = wave & 1;
    const int lrow = lane & 15, lquad = lane >> 4;

    floatx4 acc[4][4];
    #pragma unroll
    for (int mt = 0; mt < 4; ++mt)
        #pragma unroll
        for (int nt = 0; nt < 4; ++nt) acc[mt][nt] = (floatx4){0.f, 0.f, 0.f, 0.f};

    #pragma unroll
    for (int ks = 0; ks < 4; ++ks) {
        short8 bf[4];
        #pragma unroll
        for (int nt = 0; nt < 4; ++nt)
            bf[nt] = *(const short8*)(Wb + (size_t)(wn * 64 + nt * 16 + lrow) * 128 + ks * 32 + lquad * 8);
        #pragma unroll
        for (int mt = 0; mt < 4; ++mt) {
            short8 af = *(const short8*)&As[wm * 64 + mt * 16 + lrow][ks * 32 + lquad * 8];
            #pragma unroll
            for (int nt = 0; nt < 4; ++nt)
                acc[mt][nt] = __builtin_amdgcn_mfma_f32_16x16x32_bf16(af, bf[nt], acc[mt][nt], 0, 0, 0);
        }
    }

    __syncthreads();   // Es aliases As: wait for all waves' frag reads

    float bv[4];
    #pragma unroll
    for (int nt = 0; nt < 4; ++nt)
        bv[nt] = (bp != nullptr) ? bp[wn * 64 + nt * 16 + lrow] : 0.0f;

    #pragma unroll
    for (int mt = 0; mt < 4; ++mt) {
        #pragma unroll
        for (int nt = 0; nt < 4; ++nt)
            #pragma unroll
            for (int r4 = 0; r4 < 4; ++r4)
                Es[wave][lquad * 4 + r4][nt * 16 + lrow] = acc[mt][nt][r4] + bv[nt];
        #pragma unroll
        for (int it = 0; it < 2; ++it) {
            int row = it * 8 + (lane >> 3);
            int ch = lane & 7;
            float4 u = *(const float4*)&Es[wave][row][ch * 8];
            float4 v = *(const float4*)&Es[wave][row][ch * 8 + 4];
            int grow = bm * 128 + wm * 64 + mt * 16 + row;
            if (grow < NRB) {
                Pack8 pk;
                pk.h[0] = __float2bfloat16(u.x); pk.h[1] = __float2bfloat16(u.y);
                pk.h[2] = __float2bfloat16(u.z); pk.h[3] = __float2bfloat16(u.w);
                pk.h[4] = __float2bfloat16(v.x); pk.h[5] = __float2bfloat16(v.y);
                pk.h[6] = __float2bfloat16(v.z); pk.h[7] = __float2bfloat16(v.w);
                *(int4*)(op + (size_t)grow * 128 + wn * 64 + ch * 8) = pk.v;
            }
        }
    }
}

// Layer 1: BN=64. slices: {0: z_rr = r@Wl1_rr, 1: out = r@Wsum1+bsum1 (fp32),
// 2: z_br = bl@Wl1_br}.
__global__ __launch_bounds__(256, 4) void gemm_l1_kernel(
    const __hip_bfloat16* __restrict__ r, const __hip_bfloat16* __restrict__ bl,
    const __hip_bfloat16* __restrict__ WT3, const __hip_bfloat16* __restrict__ WT4,
    __hip_bfloat16* __restrict__ z_rr, __hip_bfloat16* __restrict__ z_br,
    float* __restrict__ out, const float* __restrict__ bsum1)
{
    __shared__ __align__(16) char smem_[128 * 136 * 2];   // 34816 B
    __hip_bfloat16 (*As)[136] = (__hip_bfloat16 (*)[136])smem_;
    float (*Es)[16][36] = (float (*)[16][36])smem_;       // 9216 B, aliases As

    const int tid = threadIdx.x, sz = blockIdx.x, bm = blockIdx.y;
    const __hip_bfloat16* A = (sz == 2) ? bl : r;
    const __hip_bfloat16* Wb = (sz == 2) ? WT3 : ((sz == 0) ? WT4 : WT4 + 64 * 128);
    const bool isf = (sz == 1);
    const int c = tid & 15, rbase = tid >> 4;

    #pragma unroll
    for (int p = 0; p < 8; ++p) {
        int r_ = p * 16 + rbase;
        int gr = bm * 128 + r_;
        int4 u = make_int4(0, 0, 0, 0);
        if (gr < NRB) u = *(const int4*)(A + (size_t)gr * 128 + c * 8);
        *(int4*)&As[r_][c * 8] = u;
    }
    __syncthreads();

    const int wave = tid >> 6, lane = tid & 63;
    const int wm = wave >> 1, wn = wave & 1;
    const int lrow = lane & 15, lquad = lane >> 4;

    floatx4 acc[4][2];
    #pragma unroll
    for (int mt = 0; mt < 4; ++mt)
        #pragma unroll
        for (int nt = 0; nt < 2; ++nt) acc[mt][nt] = (floatx4){0.f, 0.f, 0.f, 0.f};

    #pragma unroll
    for (int ks = 0; ks < 4; ++ks) {
        short8 bf[2];
        #pragma unroll
        for (int nt = 0; nt < 2; ++nt)
            bf[nt] = *(const short8*)(Wb + (size_t)(wn * 32 + nt * 16 + lrow) * 128 + ks * 32 + lquad * 8);
        #pragma unroll
        for (int mt = 0; mt < 4; ++mt) {
            short8 af = *(const short8*)&As[wm * 64 + mt * 16 + lrow][ks * 32 + lquad * 8];
            #pragma unroll
            for (int nt = 0; nt < 2; ++nt)
                acc[mt][nt] = __builtin_amdgcn_mfma_f32_16x16x32_bf16(af, bf[nt], acc[mt][nt], 0, 0, 0);
        }
    }

    __syncthreads();   // Es aliases As

    float bv[2];
    #pragma unroll
    for (int nt = 0; nt < 2; ++nt)
        bv[nt] = isf ? bsum1[wn * 32 + nt * 16 + lrow] : 0.0f;

    #pragma unroll
    for (int mt = 0; mt < 4; ++mt) {
        #pragma unroll
        for (int nt = 0; nt < 2; ++nt)
            #pragma unroll
            for (int r4 = 0; r4 < 4; ++r4)
                Es[wave][lquad * 4 + r4][nt * 16 + lrow] = acc[mt][nt][r4] + bv[nt];
        int row = lane >> 2, ch = lane & 3;
        float4 u = *(const float4*)&Es[wave][row][ch * 8];
        float4 v = *(const float4*)&Es[wave][row][ch * 8 + 4];
        int grow = bm * 128 + wm * 64 + mt * 16 + row;
        if (grow < NRB) {
            if (isf) {
                float* p = out + (size_t)grow * 64 + wn * 32 + ch * 8;
                *(float4*)p = u;
                *(float4*)(p + 4) = v;
            } else {
                __hip_bfloat16* op = (sz == 0) ? z_rr : z_br;
                Pack8 pk;
                pk.h[0] = __float2bfloat16(u.x); pk.h[1] = __float2bfloat16(u.y);
                pk.h[2] = __float2bfloat16(u.z); pk.h[3] = __float2bfloat16(u.w);
                pk.h[4] = __float2bfloat16(v.x); pk.h[5] = __float2bfloat16(v.y);
                pk.h[6] = __float2bfloat16(v.z); pk.h[7] = __float2bfloat16(v.w);
                *(int4*)(op + (size_t)grow * 64 + wn * 32 + ch * 8) = pk.v;
            }
        }
    }
}

// ---------------- gathers (no atomics, 4-way MLP, fused epilogues) ----------------
// Wave split into 4 groups of 16 lanes; each group walks every 4th neighbor of
// its segment, loading a full row (16B/lane for 128-d, 8B/lane for 64-d).
// Segments processed in SEPARATE branch-free loops (constant table + weight per
// loop, no per-edge selects), 2-way unrolled so two col->row dependent chains
// are in flight per group (odd-tail duplicate load hits the just-fetched line).
// Groups combined with shfl_xor(16), shfl_xor(32).

__device__ inline void facc8(const int4& u, float w, float* a) {
    float2 f0 = __bfloat1622float2(*(const __hip_bfloat162*)&u.x);
    float2 f1 = __bfloat1622float2(*(const __hip_bfloat162*)&u.y);
    float2 f2 = __bfloat1622float2(*(const __hip_bfloat162*)&u.z);
    float2 f3 = __bfloat1622float2(*(const __hip_bfloat162*)&u.w);
    a[0] = fmaf(w, f0.x, a[0]); a[1] = fmaf(w, f0.y, a[1]);
    a[2] = fmaf(w, f1.x, a[2]); a[3] = fmaf(w, f1.y, a[3]);
    a[4] = fmaf(w, f2.x, a[4]); a[5] = fmaf(w, f2.y, a[5]);
    a[6] = fmaf(w, f3.x, a[6]); a[7] = fmaf(w, f3.y, a[7]);
}

__device__ inline void unpack8(const int4& u, float* s) {
    float2 f0 = __bfloat1622float2(*(const __hip_bfloat162*)&u.x);
    float2 f1 = __bfloat1622float2(*(const __hip_bfloat162*)&u.y);
    float2 f2 = __bfloat1622float2(*(const __hip_bfloat162*)&u.z);
    float2 f3 = __bfloat1622float2(*(const __hip_bfloat162*)&u.w);
    s[0] = f0.x; s[1] = f0.y; s[2] = f1.x; s[3] = f1.y;
    s[4] = f2.x; s[5] = f2.y; s[6] = f3.x; s[7] = f3.y;
}

// 2-edge-deep gather over one CSR segment into a[8] with constant weight.
__device__ inline void seg_gather8(const __hip_bfloat16* __restrict__ tab,
                                   const int* __restrict__ col,
                                   int s, int e, int q, int c, float w, float* a) {
    for (int i = s + q; i < e; i += 8) {
        int i2 = i + 4;
        int c0 = col[i];
        int c1 = col[(i2 < e) ? i2 : i];
        int4 u0 = *(const int4*)(tab + (size_t)c0 * 128 + c * 8);
        int4 u1 = *(const int4*)(tab + (size_t)c1 * 128 + c * 8);
        facc8(u0, w, a);
        if (i2 < e) facc8(u1, w, a);
    }
}

// by=0: r[row] = relu(inv_rr*sum y_rr + inv_br*sum y_br + sr)
// by=1: bl[row] = relu(inv_rb*sum y_rb + sb)
__global__ __launch_bounds__(256) void gather_l0_kernel(
    const __hip_bfloat16* __restrict__ y_rr, const __hip_bfloat16* __restrict__ y_br,
    const __hip_bfloat16* __restrict__ sr,
    const __hip_bfloat16* __restrict__ y_rb, const __hip_bfloat16* __restrict__ sb,
    const int* __restrict__ col, const int* __restrict__ rowstart,
    const float* __restrict__ inv,
    __hip_bfloat16* __restrict__ r_out, __hip_bfloat16* __restrict__ bl_out)
{
    int row = blockIdx.x * 4 + (threadIdx.x >> 6);
    if (row >= NRB) return;
    int lane = threadIdx.x & 63;
    int q = lane >> 4, c = lane & 15;

    float a[8];
    #pragma unroll
    for (int k = 0; k < 8; ++k) a[k] = 0.f;

    const __hip_bfloat16* self;
    __hip_bfloat16* outp;

    if (blockIdx.y == 0) {
        int s1 = rowstart[row],          e1 = rowstart[row + 1];
        int s2 = rowstart[200000 + row], e2 = rowstart[200000 + row + 1];
        float ia = inv[row], ib = inv[200000 + row];
        seg_gather8(y_rr, col, s1, e1, q, c, ia, a);
        seg_gather8(y_br, col, s2, e2, q, c, ib, a);
        self = sr; outp = r_out;
    } else {
        int s1 = rowstart[100000 + row], e1 = rowstart[100000 + row + 1];
        float ia = inv[100000 + row];
        seg_gather8(y_rb, col, s1, e1, q, c, ia, a);
        self = sb; outp = bl_out;
    }

    #pragma unroll
    for (int k = 0; k < 8; ++k) {
        a[k] += __shfl_xor(a[k], 16, 64);
        a[k] += __shfl_xor(a[k], 32, 64);
    }
    if (q == 0) {
        int4 sv = *(const int4*)(self + (size_t)row * 128 + c * 8);
        float s8[8];
        unpack8(sv, s8);
        Pack8 pk;
        #pragma unroll
        for (int k = 0; k < 8; ++k)
            pk.h[k] = __float2bfloat16(fmaxf(a[k] + s8[k], 0.f));
        *(int4*)(outp + (size_t)row * 128 + c * 8) = pk.v;
    }
}

__device__ inline void facc4(const int2& u, float w, float* a) {
    float2 f0 = __bfloat1622float2(*(const __hip_bfloat162*)&u.x);
    float2 f1 = __bfloat1622float2(*(const __hip_bfloat162*)&u.y);
    a[0] = fmaf(w, f0.x, a[0]); a[1] = fmaf(w, f0.y, a[1]);
    a[2] = fmaf(w, f1.x, a[2]); a[3] = fmaf(w, f1.y, a[3]);
}

__device__ inline void seg_gather4(const __hip_bfloat16* __restrict__ tab,
                                   const int* __restrict__ col,
                                   int s, int e, int q, int c, float w, float* a) {
    for (int i = s + q; i < e; i += 8) {
        int i2 = i + 4;
        int c0 = col[i];
        int c1 = col[(i2 < e) ? i2 : i];
        int2 u0 = *(const int2*)(tab + (size_t)c0 * 64 + c * 4);
        int2 u1 = *(const int2*)(tab + (size_t)c1 * 64 + c * 4);
        facc4(u0, w, a);
        if (i2 < e) facc4(u1, w, a);
    }
}

// out[row] += inv_rr*sum z_rr[col] + inv_br*sum z_br[col]  (64-d)
__global__ __launch_bounds__(256) void gather64_dual_kernel(
    const __hip_bfloat16* __restrict__ zrr, const __hip_bfloat16* __restrict__ zbr,
    const int* __restrict__ col, const int* __restrict__ rowstart,
    const float* __restrict__ inv, float* __restrict__ out)
{
    int row = blockIdx.x * 4 + (threadIdx.x >> 6);
    if (row >= NRB) return;
    int lane = threadIdx.x & 63;
    int q = lane >> 4, c = lane & 15;   // 16 lanes x 8B = 128B row

    float a[4];
    #pragma unroll
    for (int k = 0; k < 4; ++k) a[k] = 0.f;

    int s1 = rowstart[row],          e1 = rowstart[row + 1];
    int s2 = rowstart[200000 + row], e2 = rowstart[200000 + row + 1];
    float ia = inv[row], ib = inv[200000 + row];
    seg_gather4(zrr, col, s1, e1, q, c, ia, a);
    seg_gather4(zbr, col, s2, e2, q, c, ib, a);

    #pragma unroll
    for (int k = 0; k < 4; ++k) {
        a[k] += __shfl_xor(a[k], 16, 64);
        a[k] += __shfl_xor(a[k], 32, 64);
    }
    if (q == 0) {
        float4* p = (float4*)(out + (size_t)row * 64 + c * 4);
        float4 cur = *p;
        cur.x += a[0]; cur.y += a[1]; cur.z += a[2]; cur.w += a[3];
        *p = cur;
    }
}

// ---------------- launch ----------------

extern "C" void kernel_launch(void* const* d_in, const int* in_sizes, int n_in,
                              void* d_out, int out_size, void* d_ws, size_t ws_size,
                              hipStream_t stream) {
    (void)in_sizes; (void)n_in; (void)out_size; (void)ws_size;

    const float* x_robot = (const float*)d_in[0];
    const float* x_ball  = (const float*)d_in[1];
    const int* ei_rr = (const int*)d_in[2];   // [2, E] int32
    const int* ei_rb = (const int*)d_in[3];
    const int* ei_br = (const int*)d_in[4];
    const float* Wl0_rr = (const float*)d_in[5];
    const float* Wr0_rr = (const float*)d_in[6];
    const float* b0_rr  = (const float*)d_in[7];
    const float* Wl0_rb = (const float*)d_in[8];
    const float* Wr0_rb = (const float*)d_in[9];
    const float* b0_rb  = (const float*)d_in[10];
    const float* Wl0_br = (const float*)d_in[11];
    const float* Wr0_br = (const float*)d_in[12];
    const float* b0_br  = (const float*)d_in[13];
    const float* Wl1_rr = (const float*)d_in[14];
    const float* Wr1_rr = (const float*)d_in[15];
    const float* b1_rr  = (const float*)d_in[16];
    // d_in[17..19] unused (ball output not returned)
    const float* Wl1_br = (const float*)d_in[20];
    const float* Wr1_br = (const float*)d_in[21];
    const float* b1_br  = (const float*)d_in[22];

    const size_t NBIG = (size_t)NRB * 128;
    __hip_bfloat16* S0 = (__hip_bfloat16*)d_ws;    // y_rb, later z_br
    __hip_bfloat16* S1 = S0 + NBIG;                // y_rr, later z_rr
    __hip_bfloat16* S2 = S1 + NBIG;                // y_br
    __hip_bfloat16* S3 = S2 + NBIG;                // sr, later bl
    __hip_bfloat16* S4 = S3 + NBIG;                // sb
    __hip_bfloat16* S5 = S4 + NBIG;                // r
    __hip_bfloat16* WT1 = S5 + NBIG;               // 384*128
    __hip_bfloat16* WT2 = WT1 + 384 * 128;         // 256*128
    __hip_bfloat16* WT3 = WT2 + 256 * 128;         // 64*128
    __hip_bfloat16* WT4 = WT3 + 64 * 128;          // 128*128
    int* col_all  = (int*)(WT4 + 128 * 128);       // 3*NEDGE
    int* deg      = col_all + 3 * NEDGE;           // NSEG
    int* cursor   = deg + NSEG;                    // NSEG (adjacent: one memset)
    int* rowstart = cursor + NSEG;                 // NSEG+32
    int* bsum     = rowstart + NSEG + 32;          // 512
    float* inv    = (float*)(bsum + 512);          // NSEG
    float* bsum0  = inv + NSEG;                    // 128
    float* bsum1  = bsum0 + 128;                   // 64

    __hip_bfloat16* y_rb = S0; __hip_bfloat16* z_br = S0;
    __hip_bfloat16* y_rr = S1; __hip_bfloat16* z_rr = S1;
    __hip_bfloat16* y_br = S2;
    __hip_bfloat16* sr = S3;   __hip_bfloat16* bl = S3;
    __hip_bfloat16* sb = S4;
    __hip_bfloat16* r  = S5;

    const int SCAN_BLOCKS = (NSEG + 1024) / 1024;  // 293
    const int eblocks = (NEDGE + 255) / 256;       // 2344
    const int gm = (NRB + 127) / 128;              // 782
    const int rblocks = (NRB + 3) / 4;

    // ---- CSR build ----
    hipMemsetAsync(deg, 0, 2 * NSEG * sizeof(int), stream);
    deg_all_kernel<<<dim3(eblocks, 3), 256, 0, stream>>>(ei_rr, ei_rb, ei_br, deg);
    scan1_kernel<<<SCAN_BLOCKS, 256, 0, stream>>>(deg, rowstart, bsum);
    scan2_kernel<<<1, 512, 0, stream>>>(bsum, SCAN_BLOCKS);
    scan3_inv_kernel<<<SCAN_BLOCKS, 256, 0, stream>>>(rowstart, bsum, deg, inv);
    fill_all_kernel<<<dim3(eblocks, 3), 256, 0, stream>>>(ei_rr, ei_rb, ei_br,
        rowstart, cursor, col_all);

    // ---- weight prep ----
    wprep_all_kernel<<<dim3(64, 9), 256, 0, stream>>>(
        Wl0_rb, Wl0_rr, Wr0_rr, Wr0_br, Wl0_br, Wr0_rb,
        Wl1_br, Wl1_rr, Wr1_rr, Wr1_br,
        b0_rr, b0_br, b1_rr, b1_br,
        WT1, WT2, WT3, WT4, bsum0, bsum1);

    // ---- layer 0 ----
    gemm_l0_kernel<<<dim3(5, gm), 256, 0, stream>>>(x_robot, x_ball, WT1, WT2,
        y_rb, y_rr, sr, y_br, sb, bsum0, b0_rb);
    gather_l0_kernel<<<dim3(rblocks, 2), 256, 0, stream>>>(y_rr, y_br, sr, y_rb, sb,
        col_all, rowstart, inv, r, bl);

    // ---- layer 1 ----
    gemm_l1_kernel<<<dim3(3, gm), 256, 0, stream>>>(r, bl, WT3, WT4, z_rr, z_br,
        (float*)d_out, bsum1);
    gather64_dual_kernel<<<rblocks, 256, 0, stream>>>(z_rr, z_br, col_all, rowstart,
        inv, (float*)d_out);
}